// Round 1
// baseline (186.270 us; speedup 1.0000x reference)
//
#include <hip/hip_runtime.h>

#define NBANCH 10
#define NCLS   14
#define LCH    19
#define NOBJ   256
#define BBATCH 8
#define HH     96
#define WW     96
#define NCHTOT 190                    // NBANCH*LCH
#define PLANE  (HH*WW)                // 9216
#define TOTCONF (BBATCH*NBANCH*PLANE) // 737280

__device__ __forceinline__ float ldat(const float* __restrict__ p, int b, int c, int hw) {
    return p[(size_t)(b * NCHTOT + c) * PLANE + hw];
}

// ---------------- Kernel 1: sum over all conf channels of (tc - pc)^2 ----------------
__global__ __launch_bounds__(256) void conf_sq_sum(const float* __restrict__ pred,
                                                   const float* __restrict__ targ,
                                                   double* __restrict__ acc) {
    int tid = blockIdx.x * 256 + threadIdx.x;          // 0 .. 184319 (720 blocks)
    int plane = tid / 2304;                            // 2304 float4 per 9216-plane
    int r = tid - plane * 2304;
    int b = plane / NBANCH;
    int g = plane - b * NBANCH;
    size_t off = (size_t)(b * NCHTOT + g * LCH) * PLANE + (size_t)r * 4;
    float4 t4 = *reinterpret_cast<const float4*>(targ + off);
    float4 p4 = *reinterpret_cast<const float4*>(pred + off);
    float dx = t4.x - p4.x, dy = t4.y - p4.y, dz = t4.z - p4.z, dw = t4.w - p4.w;
    double s = (double)(dx*dx) + (double)(dy*dy) + (double)(dz*dz) + (double)(dw*dw);
    for (int o = 32; o > 0; o >>= 1) s += __shfl_down(s, o, 64);
    __shared__ double wsum[4];
    int lane = threadIdx.x & 63, wid = threadIdx.x >> 6;
    if (lane == 0) wsum[wid] = s;
    __syncthreads();
    if (threadIdx.x == 0) {
        atomicAdd(acc, wsum[0] + wsum[1] + wsum[2] + wsum[3]);
    }
}

// ---------------- Kernel 2: everything else (1 block, 256 threads) ----------------
__global__ __launch_bounds__(256) void yolo_main(const float* __restrict__ pred,
                                                 const float* __restrict__ targ,
                                                 const int* __restrict__ grids,
                                                 const double* __restrict__ acc,
                                                 float* __restrict__ out) {
    __shared__ int packed[NOBJ];                    // (b<<24)|(g<<16)|(h<<8)|w
    __shared__ float iou_s[NOBJ][NBANCH];
    __shared__ int sels[NOBJ];
    __shared__ unsigned long long maskw[NOBJ][4];
    __shared__ unsigned long long Sword[4];
    __shared__ int keys[NOBJ];
    __shared__ double red[NOBJ][4];

    const int i = threadIdx.x;
    const int b = grids[i*4+0], g = grids[i*4+1], h = grids[i*4+2], w = grids[i*4+3];
    packed[i] = (b << 24) | (g << 16) | (h << 8) | w;
    const int hw = h * WW + w;

    // ---- target box (corners exactly as reference computes them) ----
    const float tx = ldat(targ, b, g*LCH+1, hw);
    const float ty = ldat(targ, b, g*LCH+2, hw);
    const float tw = ldat(targ, b, g*LCH+3, hw);
    const float th = ldat(targ, b, g*LCH+4, hw);
    const float tb0 = tx - tw*0.5f, tb1 = ty - th*0.5f;
    const float tb2 = tx + tw*0.5f, tb3 = ty + th*0.5f;
    const float ta  = fabsf((tb2 - tb0) * (tb3 - tb1));

    // ---- IoU row vs all 10 anchors; afirst = min{a>=1 : iou>0} (exact result when
    //      the row-match mask is empty, since iou < 1 <= cur blocks all later a) ----
    int afirst = 0;
    #pragma unroll
    for (int a = 0; a < NBANCH; ++a) {
        float px = ldat(pred, b, a*LCH+1, hw);
        float py = ldat(pred, b, a*LCH+2, hw);
        float pw = ldat(pred, b, a*LCH+3, hw);
        float ph = ldat(pred, b, a*LCH+4, hw);
        float pb0 = px - pw*0.5f, pb1 = py - ph*0.5f;
        float pb2 = px + pw*0.5f, pb3 = py + ph*0.5f;
        float x1 = fmaxf(tb0, pb0), y1 = fmaxf(tb1, pb1);
        float x2 = fminf(tb2, pb2), y2 = fminf(tb3, pb3);
        float inter = fmaxf(x2 - x1, 0.f) * fmaxf(y2 - y1, 0.f);
        float pa = fabsf((pb2 - pb0) * (pb3 - pb1));
        float v = inter / (((ta + pa) - inter) + 1e-6f);
        iou_s[i][a] = v;
        if (a >= 1 && afirst == 0 && v > 0.f) afirst = a;
    }
    sels[i] = afirst;          // provisional final; exact for empty-mask grids
    __syncthreads();

    // ---- row-match mask: j matches iff b_j==b_i && g_j==h_i && h_j==w_i ----
    const int mkey = (b << 16) | (h << 8) | w;
    unsigned long long m0 = 0, m1 = 0, m2 = 0, m3 = 0;
    for (int j = 0; j < NOBJ; ++j) {
        if ((packed[j] >> 8) == mkey) {
            if (j < 64)       m0 |= 1ull << j;
            else if (j < 128) m1 |= 1ull << (j - 64);
            else if (j < 192) m2 |= 1ull << (j - 128);
            else              m3 |= 1ull << (j - 192);
        }
    }
    maskw[i][0] = m0; maskw[i][1] = m1; maskw[i][2] = m2; maskw[i][3] = m3;
    const bool inS = (m0 | m1 | m2 | m3) != 0ull;
    unsigned long long bal = __ballot(inS);
    if ((i & 63) == 0) Sword[i >> 6] = bal;
    __syncthreads();

    // ---- exact sequential emulation, but only for grids with nonempty masks.
    //      At grid k's scan step: cell j holds final value if j<k, 0 if j>k, cur if j==k. ----
    if (i == 0) {
        for (int wd0 = 0; wd0 < 4; ++wd0) {
            unsigned long long sw = Sword[wd0];
            while (sw) {
                int k = wd0 * 64 + __ffsll((long long)sw) - 1;
                sw &= sw - 1;
                unsigned long long km[4] = {maskw[k][0], maskw[k][1], maskw[k][2], maskw[k][3]};
                int kc = __popcll(km[0]) + __popcll(km[1]) + __popcll(km[2]) + __popcll(km[3]);
                float kiou[NBANCH];
                #pragma unroll
                for (int a = 0; a < NBANCH; ++a) kiou[a] = iou_s[k][a];
                int cur = 0;
                for (int a = 0; a < NBANCH; ++a) {
                    if ((float)cur < kiou[a]) {
                        bool ok = (a != 0) || (kc == 96);
                        if (ok) {
                            for (int wd = 0; wd < 4 && ok; ++wd) {
                                unsigned long long mm = km[wd];
                                while (mm) {
                                    int j = wd * 64 + __ffsll((long long)mm) - 1;
                                    mm &= mm - 1;
                                    int vj = (j == k) ? cur : (j < k ? sels[j] : 0);
                                    if (vj == a) { ok = false; break; }
                                }
                            }
                        }
                        if (ok) cur = a;
                    }
                }
                sels[k] = cur;
            }
        }
    }
    __syncthreads();

    const int sel = sels[i];
    // ---- sel_xy = maxI[b, g, h, w=h]: nonzero only if that cell is a valid grid ----
    const int pkxy = (b << 24) | (g << 16) | (h << 8) | h;
    int sxy = 0;
    for (int j = 0; j < NOBJ; ++j) if (packed[j] == pkxy) sxy = sels[j];

    keys[i] = ((b * NBANCH + sel) * HH + h) * WW + w;
    __syncthreads();
    bool firstocc = true;
    for (int j = 0; j < i; ++j) if (keys[j] == keys[i]) { firstocc = false; break; }

    // ---- per-grid losses ----
    float px_s = ldat(pred, b, sxy*LCH+1, hw);
    float py_s = ldat(pred, b, sxy*LCH+2, hw);
    float dxl = tx - px_s, dyl = ty - py_s;
    float dwl = sqrtf(fmaxf(tw, 0.f)) - sqrtf(fmaxf(ldat(pred, b, sel*LCH+3, hw), 0.f));
    float dhl = sqrtf(fmaxf(th, 0.f)) - sqrtf(fmaxf(ldat(pred, b, sel*LCH+4, hw), 0.f));
    double loc = (double)(dxl*dxl) + (double)(dyl*dyl) + (double)(dwl*dwl) + (double)(dhl*dhl);

    float dco = ldat(targ, b, g*LCH, hw) - ldat(pred, b, sel*LCH, hw);
    double co = (double)(dco*dco);

    float clsf = 0.f;
    #pragma unroll
    for (int c = 0; c < NCLS; ++c) {
        float d = ldat(pred, b, sel*LCH+5+c, hw) - ldat(targ, b, b*LCH+5+c, hw);
        clsf += d * d;
    }
    double cls = (double)(clsf / 14.f);

    double sub = 0.0;
    if (firstocc) {
        float d = ldat(targ, b, sel*LCH, hw) - ldat(pred, b, sel*LCH, hw);
        sub = (double)(d * d);
    }

    red[i][0] = loc; red[i][1] = co; red[i][2] = cls; red[i][3] = sub;
    __syncthreads();
    for (int s = 128; s > 0; s >>= 1) {
        if (i < s) {
            red[i][0] += red[i+s][0];
            red[i][1] += red[i+s][1];
            red[i][2] += red[i+s][2];
            red[i][3] += red[i+s][3];
        }
        __syncthreads();
    }
    if (i == 0) {
        double Sbig = *acc;
        double locS = red[0][0] / 256.0;
        double coS  = red[0][1] / 256.0;
        double clsS = red[0][2] / 256.0;
        double cn   = (Sbig - red[0][3]) / (double)TOTCONF;
        out[0] = (float)(7.0 * locS + 5.0 * coS + 5.0 * cn + clsS);
    }
}

extern "C" void kernel_launch(void* const* d_in, const int* in_sizes, int n_in,
                              void* d_out, int out_size, void* d_ws, size_t ws_size,
                              hipStream_t stream) {
    const float* pred = (const float*)d_in[0];
    const float* targ = (const float*)d_in[1];
    const int*  grids = (const int*)d_in[2];
    float* out = (float*)d_out;
    double* acc = (double*)d_ws;

    hipMemsetAsync(d_ws, 0, sizeof(double), stream);
    conf_sq_sum<<<720, 256, 0, stream>>>(pred, targ, acc);
    yolo_main<<<1, 256, 0, stream>>>(pred, targ, grids, acc, out);
}

// Round 2
// 165.419 us; speedup vs baseline: 1.1260x; 1.1260x over previous
//
#include <hip/hip_runtime.h>

#define NBANCH 10
#define NCLS   14
#define LCH    19
#define NOBJ   256
#define BBATCH 8
#define HH     96
#define WW     96
#define NCHTOT 190                    // NBANCH*LCH
#define PLANE  (HH*WW)                // 9216
#define TOTCONF (BBATCH*NBANCH*PLANE) // 737280
#define NCONFBLK 720

__device__ __forceinline__ float ldat(const float* __restrict__ p, int b, int c, int hw) {
    return p[(size_t)(b * NCHTOT + c) * PLANE + hw];
}

// ws float layout (after 720 doubles of conf partials)
#define IOU_OFF 0
#define XY_OFF  2560
#define WH_OFF  5120
#define CO_OFF  7680
#define CLS_OFF 10240
#define SUB_OFF 12800

// ---------------- Kernel A: conf-sum partials (blocks 0..719) + per-grid/anchor
//                  gather+precompute (blocks 720..975) ----------------
__global__ __launch_bounds__(256) void fused_pre(const float* __restrict__ pred,
                                                 const float* __restrict__ targ,
                                                 const int* __restrict__ grids,
                                                 double* __restrict__ conf_part,
                                                 float* __restrict__ gw) {
    if (blockIdx.x < NCONFBLK) {
        int tid = blockIdx.x * 256 + threadIdx.x;          // 0 .. 184319
        int plane = tid / 2304;                            // 2304 float4 per plane
        int r = tid - plane * 2304;
        int b = plane / NBANCH;
        int g = plane - b * NBANCH;
        size_t off = (size_t)(b * NCHTOT + g * LCH) * PLANE + (size_t)r * 4;
        float4 t4 = *reinterpret_cast<const float4*>(targ + off);
        float4 p4 = *reinterpret_cast<const float4*>(pred + off);
        float dx = t4.x - p4.x, dy = t4.y - p4.y, dz = t4.z - p4.z, dw = t4.w - p4.w;
        double s = (double)(dx*dx) + (double)(dy*dy) + (double)(dz*dz) + (double)(dw*dw);
        for (int o = 32; o > 0; o >>= 1) s += __shfl_down(s, o, 64);
        __shared__ double wsum[4];
        int lane = threadIdx.x & 63, wid = threadIdx.x >> 6;
        if (lane == 0) wsum[wid] = s;
        __syncthreads();
        if (threadIdx.x == 0) conf_part[blockIdx.x] = wsum[0] + wsum[1] + wsum[2] + wsum[3];
        return;
    }

    // gather blocks: one grid each, threads 0..9 = anchors
    int gi = blockIdx.x - NCONFBLK;
    int a = threadIdx.x;
    if (a >= NBANCH) return;
    const int b = grids[gi*4+0], g = grids[gi*4+1], h = grids[gi*4+2], w = grids[gi*4+3];
    const int hw = h * WW + w;

    const float tc = ldat(targ, b, g*LCH+0, hw);
    const float tx = ldat(targ, b, g*LCH+1, hw);
    const float ty = ldat(targ, b, g*LCH+2, hw);
    const float tw = ldat(targ, b, g*LCH+3, hw);
    const float th = ldat(targ, b, g*LCH+4, hw);
    const float tb0 = tx - tw*0.5f, tb1 = ty - th*0.5f;
    const float tb2 = tx + tw*0.5f, tb3 = ty + th*0.5f;
    const float ta  = fabsf((tb2 - tb0) * (tb3 - tb1));

    const float pc = ldat(pred, b, a*LCH+0, hw);
    const float px = ldat(pred, b, a*LCH+1, hw);
    const float py = ldat(pred, b, a*LCH+2, hw);
    const float pw = ldat(pred, b, a*LCH+3, hw);
    const float ph = ldat(pred, b, a*LCH+4, hw);
    const float tca = ldat(targ, b, a*LCH+0, hw);   // targ conf at anchor a's channel

    const float pb0 = px - pw*0.5f, pb1 = py - ph*0.5f;
    const float pb2 = px + pw*0.5f, pb3 = py + ph*0.5f;
    float x1 = fmaxf(tb0, pb0), y1 = fmaxf(tb1, pb1);
    float x2 = fminf(tb2, pb2), y2 = fminf(tb3, pb3);
    float inter = fmaxf(x2 - x1, 0.f) * fmaxf(y2 - y1, 0.f);
    float pa = fabsf((pb2 - pb0) * (pb3 - pb1));
    float iou = inter / (((ta + pa) - inter) + 1e-6f);

    float dxl = tx - px, dyl = ty - py;
    float xy  = dxl*dxl + dyl*dyl;
    float dwl = sqrtf(fmaxf(tw, 0.f)) - sqrtf(fmaxf(pw, 0.f));
    float dhl = sqrtf(fmaxf(th, 0.f)) - sqrtf(fmaxf(ph, 0.f));
    float wh  = dwl*dwl + dhl*dhl;
    float dco = tc - pc;
    float co  = dco*dco;
    float dsb = tca - pc;
    float sub = dsb*dsb;

    float clsf = 0.f;
    #pragma unroll
    for (int c = 0; c < NCLS; ++c) {
        float d = ldat(pred, b, a*LCH+5+c, hw) - ldat(targ, b, b*LCH+5+c, hw);
        clsf += d * d;
    }
    float cls = clsf / 14.f;

    int idx = gi * NBANCH + a;
    gw[IOU_OFF + idx] = iou;
    gw[XY_OFF  + idx] = xy;
    gw[WH_OFF  + idx] = wh;
    gw[CO_OFF  + idx] = co;
    gw[CLS_OFF + idx] = cls;
    gw[SUB_OFF + idx] = sub;
}

// ---------------- Kernel B: serial sel + combine (1 block, 256 threads) ----------------
__global__ __launch_bounds__(256) void yolo_main(const int* __restrict__ grids,
                                                 const double* __restrict__ conf_part,
                                                 const float* __restrict__ gw,
                                                 float* __restrict__ out) {
    __shared__ int packed[NOBJ];                    // (b<<24)|(g<<16)|(h<<8)|w
    __shared__ float iou_s[NOBJ][NBANCH];
    __shared__ int sels[NOBJ];
    __shared__ unsigned long long maskw[NOBJ][4];
    __shared__ unsigned long long Sword[4];
    __shared__ int keys[NOBJ];
    __shared__ double red[NOBJ][5];

    const int i = threadIdx.x;
    const int b = grids[i*4+0], g = grids[i*4+1], h = grids[i*4+2], w = grids[i*4+3];
    packed[i] = (b << 24) | (g << 16) | (h << 8) | w;

    int afirst = 0;
    #pragma unroll
    for (int a = 0; a < NBANCH; ++a) {
        float v = gw[IOU_OFF + i*NBANCH + a];
        iou_s[i][a] = v;
        if (a >= 1 && afirst == 0 && v > 0.f) afirst = a;
    }
    sels[i] = afirst;          // exact for empty-mask grids (iou < 1 <= cur blocks updates)
    __syncthreads();

    // ---- row-match mask: j matches iff b_j==b_i && g_j==h_i && h_j==w_i ----
    const int mkey = (b << 16) | (h << 8) | w;
    unsigned long long m0 = 0, m1 = 0, m2 = 0, m3 = 0;
    for (int j = 0; j < NOBJ; ++j) {
        if ((packed[j] >> 8) == mkey) {
            if (j < 64)       m0 |= 1ull << j;
            else if (j < 128) m1 |= 1ull << (j - 64);
            else if (j < 192) m2 |= 1ull << (j - 128);
            else              m3 |= 1ull << (j - 192);
        }
    }
    maskw[i][0] = m0; maskw[i][1] = m1; maskw[i][2] = m2; maskw[i][3] = m3;
    const bool inS = (m0 | m1 | m2 | m3) != 0ull;
    unsigned long long bal = __ballot(inS);
    if ((i & 63) == 0) Sword[i >> 6] = bal;
    __syncthreads();

    // ---- exact sequential emulation for mask-nonempty grids only ----
    if (i == 0) {
        for (int wd0 = 0; wd0 < 4; ++wd0) {
            unsigned long long sw = Sword[wd0];
            while (sw) {
                int k = wd0 * 64 + __ffsll((long long)sw) - 1;
                sw &= sw - 1;
                unsigned long long km[4] = {maskw[k][0], maskw[k][1], maskw[k][2], maskw[k][3]};
                int kc = __popcll(km[0]) + __popcll(km[1]) + __popcll(km[2]) + __popcll(km[3]);
                int cur = 0;
                for (int a = 0; a < NBANCH; ++a) {
                    if ((float)cur < iou_s[k][a]) {
                        bool ok = (a != 0) || (kc == 96);
                        if (ok) {
                            for (int wd = 0; wd < 4 && ok; ++wd) {
                                unsigned long long mm = km[wd];
                                while (mm) {
                                    int j = wd * 64 + __ffsll((long long)mm) - 1;
                                    mm &= mm - 1;
                                    int vj = (j == k) ? cur : (j < k ? sels[j] : 0);
                                    if (vj == a) { ok = false; break; }
                                }
                            }
                        }
                        if (ok) cur = a;
                    }
                }
                sels[k] = cur;
            }
        }
    }
    __syncthreads();

    const int sel = sels[i];
    // ---- sel_xy = maxI[b, g, h, w=h]: nonzero only if that cell is a valid grid ----
    const int pkxy = (b << 24) | (g << 16) | (h << 8) | h;
    int sxy = 0;
    for (int j = 0; j < NOBJ; ++j) if (packed[j] == pkxy) sxy = sels[j];

    keys[i] = ((b * NBANCH + sel) * HH + h) * WW + w;
    __syncthreads();
    bool firstocc = true;
    for (int j = 0; j < i; ++j) if (keys[j] == keys[i]) { firstocc = false; break; }

    // ---- pick precomputed pieces ----
    double loc = (double)gw[XY_OFF + i*NBANCH + sxy] + (double)gw[WH_OFF + i*NBANCH + sel];
    double co  = (double)gw[CO_OFF + i*NBANCH + sel];
    double cls = (double)gw[CLS_OFF + i*NBANCH + sel];
    double sub = firstocc ? (double)gw[SUB_OFF + i*NBANCH + sel] : 0.0;

    // conf partial pickup: 720 doubles across 256 threads
    double cp = conf_part[i];
    if (i + 256 < NCONFBLK) cp += conf_part[i + 256];
    if (i + 512 < NCONFBLK) cp += conf_part[i + 512];

    red[i][0] = loc; red[i][1] = co; red[i][2] = cls; red[i][3] = sub; red[i][4] = cp;
    __syncthreads();
    for (int s = 128; s > 0; s >>= 1) {
        if (i < s) {
            red[i][0] += red[i+s][0];
            red[i][1] += red[i+s][1];
            red[i][2] += red[i+s][2];
            red[i][3] += red[i+s][3];
            red[i][4] += red[i+s][4];
        }
        __syncthreads();
    }
    if (i == 0) {
        double locS = red[0][0] / 256.0;
        double coS  = red[0][1] / 256.0;
        double clsS = red[0][2] / 256.0;
        double cn   = (red[0][4] - red[0][3]) / (double)TOTCONF;
        out[0] = (float)(7.0 * locS + 5.0 * coS + 5.0 * cn + clsS);
    }
}

extern "C" void kernel_launch(void* const* d_in, const int* in_sizes, int n_in,
                              void* d_out, int out_size, void* d_ws, size_t ws_size,
                              hipStream_t stream) {
    const float* pred = (const float*)d_in[0];
    const float* targ = (const float*)d_in[1];
    const int*  grids = (const int*)d_in[2];
    float* out = (float*)d_out;
    double* conf_part = (double*)d_ws;                       // 720 doubles
    float* gw = (float*)((char*)d_ws + NCONFBLK * sizeof(double));

    fused_pre<<<NCONFBLK + NOBJ, 256, 0, stream>>>(pred, targ, grids, conf_part, gw);
    yolo_main<<<1, 256, 0, stream>>>(grids, conf_part, gw, out);
}

// Round 3
// 159.502 us; speedup vs baseline: 1.1678x; 1.0371x over previous
//
#include <hip/hip_runtime.h>

#define NBANCH 10
#define NCLS   14
#define LCH    19
#define NOBJ   256
#define BBATCH 8
#define HH     96
#define WW     96
#define NCHTOT 190                    // NBANCH*LCH
#define PLANE  (HH*WW)                // 9216
#define TOTCONF (BBATCH*NBANCH*PLANE) // 737280
#define NCONFBLK 720

__device__ __forceinline__ float ldat(const float* __restrict__ p, int b, int c, int hw) {
    return p[(size_t)(b * NCHTOT + c) * PLANE + hw];
}

// ws float layout (after 720 doubles of conf partials)
#define IOU_OFF 0
#define XY_OFF  2560
#define WH_OFF  5120
#define CO_OFF  7680
#define CLS_OFF 10240
#define SUB_OFF 12800

// ---------------- Kernel A: conf-sum partials (blocks 0..719) + per-grid/anchor
//                  gather+precompute (blocks 720..975) ----------------
__global__ __launch_bounds__(256) void fused_pre(const float* __restrict__ pred,
                                                 const float* __restrict__ targ,
                                                 const int* __restrict__ grids,
                                                 double* __restrict__ conf_part,
                                                 float* __restrict__ gw) {
    if (blockIdx.x < NCONFBLK) {
        int tid = blockIdx.x * 256 + threadIdx.x;          // 0 .. 184319
        int plane = tid / 2304;                            // 2304 float4 per plane
        int r = tid - plane * 2304;
        int b = plane / NBANCH;
        int g = plane - b * NBANCH;
        size_t off = (size_t)(b * NCHTOT + g * LCH) * PLANE + (size_t)r * 4;
        float4 t4 = *reinterpret_cast<const float4*>(targ + off);
        float4 p4 = *reinterpret_cast<const float4*>(pred + off);
        float dx = t4.x - p4.x, dy = t4.y - p4.y, dz = t4.z - p4.z, dw = t4.w - p4.w;
        double s = (double)(dx*dx) + (double)(dy*dy) + (double)(dz*dz) + (double)(dw*dw);
        for (int o = 32; o > 0; o >>= 1) s += __shfl_down(s, o, 64);
        __shared__ double wsum[4];
        int lane = threadIdx.x & 63, wid = threadIdx.x >> 6;
        if (lane == 0) wsum[wid] = s;
        __syncthreads();
        if (threadIdx.x == 0) conf_part[blockIdx.x] = wsum[0] + wsum[1] + wsum[2] + wsum[3];
        return;
    }

    // gather blocks: one grid each, threads 0..9 = anchors
    int gi = blockIdx.x - NCONFBLK;
    int a = threadIdx.x;
    if (a >= NBANCH) return;
    const int b = grids[gi*4+0], g = grids[gi*4+1], h = grids[gi*4+2], w = grids[gi*4+3];
    const int hw = h * WW + w;

    const float tc = ldat(targ, b, g*LCH+0, hw);
    const float tx = ldat(targ, b, g*LCH+1, hw);
    const float ty = ldat(targ, b, g*LCH+2, hw);
    const float tw = ldat(targ, b, g*LCH+3, hw);
    const float th = ldat(targ, b, g*LCH+4, hw);
    const float tb0 = tx - tw*0.5f, tb1 = ty - th*0.5f;
    const float tb2 = tx + tw*0.5f, tb3 = ty + th*0.5f;
    const float ta  = fabsf((tb2 - tb0) * (tb3 - tb1));

    const float pc = ldat(pred, b, a*LCH+0, hw);
    const float px = ldat(pred, b, a*LCH+1, hw);
    const float py = ldat(pred, b, a*LCH+2, hw);
    const float pw = ldat(pred, b, a*LCH+3, hw);
    const float ph = ldat(pred, b, a*LCH+4, hw);
    const float tca = ldat(targ, b, a*LCH+0, hw);   // targ conf at anchor a's channel

    const float pb0 = px - pw*0.5f, pb1 = py - ph*0.5f;
    const float pb2 = px + pw*0.5f, pb3 = py + ph*0.5f;
    float x1 = fmaxf(tb0, pb0), y1 = fmaxf(tb1, pb1);
    float x2 = fminf(tb2, pb2), y2 = fminf(tb3, pb3);
    float inter = fmaxf(x2 - x1, 0.f) * fmaxf(y2 - y1, 0.f);
    float pa = fabsf((pb2 - pb0) * (pb3 - pb1));
    float iou = inter / (((ta + pa) - inter) + 1e-6f);

    float dxl = tx - px, dyl = ty - py;
    float xy  = dxl*dxl + dyl*dyl;
    float dwl = sqrtf(fmaxf(tw, 0.f)) - sqrtf(fmaxf(pw, 0.f));
    float dhl = sqrtf(fmaxf(th, 0.f)) - sqrtf(fmaxf(ph, 0.f));
    float wh  = dwl*dwl + dhl*dhl;
    float dco = tc - pc;
    float co  = dco*dco;
    float dsb = tca - pc;
    float sub = dsb*dsb;

    float clsf = 0.f;
    #pragma unroll
    for (int c = 0; c < NCLS; ++c) {
        float d = ldat(pred, b, a*LCH+5+c, hw) - ldat(targ, b, b*LCH+5+c, hw);
        clsf += d * d;
    }
    float cls = clsf / 14.f;

    int idx = gi * NBANCH + a;
    gw[IOU_OFF + idx] = iou;
    gw[XY_OFF  + idx] = xy;
    gw[WH_OFF  + idx] = wh;
    gw[CO_OFF  + idx] = co;
    gw[CLS_OFF + idx] = cls;
    gw[SUB_OFF + idx] = sub;
}

// ---------------- Kernel B: parallel-Jacobi sel + combine (1 block, 256 threads) ----------------
__global__ __launch_bounds__(256) void yolo_main(const int* __restrict__ grids,
                                                 const double* __restrict__ conf_part,
                                                 const float* __restrict__ gw,
                                                 float* __restrict__ out) {
    __shared__ int packed[NOBJ];                    // (b<<24)|(g<<16)|(h<<8)|w
    __shared__ int sels[NOBJ];
    __shared__ int keys[NOBJ];
    __shared__ int changed;
    __shared__ double red[NOBJ][5];

    const int i = threadIdx.x;
    const int b = grids[i*4+0], g = grids[i*4+1], h = grids[i*4+2], w = grids[i*4+3];
    packed[i] = (b << 24) | (g << 16) | (h << 8) | w;

    // own IoU row in registers
    float iou_r[NBANCH];
    int afirst = 0;
    #pragma unroll
    for (int a = 0; a < NBANCH; ++a) {
        float v = gw[IOU_OFF + i*NBANCH + a];
        iou_r[a] = v;
        if (a >= 1 && afirst == 0 && v > 0.f) afirst = a;
    }
    sels[i] = afirst;          // exact for empty-mask grids (iou < 1 <= cur blocks updates)
    __syncthreads();

    // ---- row-match mask (registers): j matches iff b_j==b_i && g_j==h_i && h_j==w_i ----
    const int mkey = (b << 16) | (h << 8) | w;
    unsigned long long mreg[4] = {0ull, 0ull, 0ull, 0ull};
    for (int j = 0; j < NOBJ; ++j) {
        if ((packed[j] >> 8) == mkey) mreg[j >> 6] |= 1ull << (j & 63);
    }
    const bool inS = (mreg[0] | mreg[1] | mreg[2] | mreg[3]) != 0ull;
    const int kc = __popcll(mreg[0]) + __popcll(mreg[1]) + __popcll(mreg[2]) + __popcll(mreg[3]);

    // ---- parallel Jacobi relaxation to the unique DAG fixpoint.
    //      Reference scan at step k sees: j<k final, j>k zero, j==k the live cur. ----
    for (int round = 0; round < NOBJ; ++round) {
        if (i == 0) changed = 0;
        __syncthreads();
        int nv = sels[i];
        if (inS) {
            int cur = 0;
            #pragma unroll
            for (int a = 0; a < NBANCH; ++a) {
                if ((float)cur < iou_r[a]) {
                    bool ok = (a != 0) || (kc == 96);
                    if (ok) {
                        #pragma unroll
                        for (int wd = 0; wd < 4; ++wd) {
                            unsigned long long mm = mreg[wd];
                            while (mm && ok) {
                                int j = wd * 64 + __ffsll((long long)mm) - 1;
                                mm &= mm - 1;
                                int vj = (j == i) ? cur : (j < i ? sels[j] : 0);
                                if (vj == a) ok = false;
                            }
                        }
                    }
                    if (ok) cur = a;
                }
            }
            nv = cur;
        }
        __syncthreads();                 // all reads of sels done before any write
        if (inS && nv != sels[i]) { sels[i] = nv; changed = 1; }
        __syncthreads();
        if (!changed) break;
    }

    const int sel = sels[i];
    // ---- sel_xy = maxI[b, g, h, w=h]: nonzero only if that cell is a valid grid ----
    const int pkxy = (b << 24) | (g << 16) | (h << 8) | h;
    int sxy = 0;
    for (int j = 0; j < NOBJ; ++j) if (packed[j] == pkxy) sxy = sels[j];

    keys[i] = ((b * NBANCH + sel) * HH + h) * WW + w;
    __syncthreads();
    bool firstocc = true;
    for (int j = 0; j < i; ++j) if (keys[j] == keys[i]) { firstocc = false; break; }

    // ---- pick precomputed pieces ----
    double loc = (double)gw[XY_OFF + i*NBANCH + sxy] + (double)gw[WH_OFF + i*NBANCH + sel];
    double co  = (double)gw[CO_OFF + i*NBANCH + sel];
    double cls = (double)gw[CLS_OFF + i*NBANCH + sel];
    double sub = firstocc ? (double)gw[SUB_OFF + i*NBANCH + sel] : 0.0;

    // conf partial pickup: 720 doubles across 256 threads
    double cp = conf_part[i];
    if (i + 256 < NCONFBLK) cp += conf_part[i + 256];
    if (i + 512 < NCONFBLK) cp += conf_part[i + 512];

    red[i][0] = loc; red[i][1] = co; red[i][2] = cls; red[i][3] = sub; red[i][4] = cp;
    __syncthreads();
    for (int s = 128; s > 0; s >>= 1) {
        if (i < s) {
            red[i][0] += red[i+s][0];
            red[i][1] += red[i+s][1];
            red[i][2] += red[i+s][2];
            red[i][3] += red[i+s][3];
            red[i][4] += red[i+s][4];
        }
        __syncthreads();
    }
    if (i == 0) {
        double locS = red[0][0] / 256.0;
        double coS  = red[0][1] / 256.0;
        double clsS = red[0][2] / 256.0;
        double cn   = (red[0][4] - red[0][3]) / (double)TOTCONF;
        out[0] = (float)(7.0 * locS + 5.0 * coS + 5.0 * cn + clsS);
    }
}

extern "C" void kernel_launch(void* const* d_in, const int* in_sizes, int n_in,
                              void* d_out, int out_size, void* d_ws, size_t ws_size,
                              hipStream_t stream) {
    const float* pred = (const float*)d_in[0];
    const float* targ = (const float*)d_in[1];
    const int*  grids = (const int*)d_in[2];
    float* out = (float*)d_out;
    double* conf_part = (double*)d_ws;                       // 720 doubles
    float* gw = (float*)((char*)d_ws + NCONFBLK * sizeof(double));

    fused_pre<<<NCONFBLK + NOBJ, 256, 0, stream>>>(pred, targ, grids, conf_part, gw);
    yolo_main<<<1, 256, 0, stream>>>(grids, conf_part, gw, out);
}

// Round 4
// 132.302 us; speedup vs baseline: 1.4079x; 1.2056x over previous
//
#include <hip/hip_runtime.h>

#define NBANCH 10
#define NCLS   14
#define LCH    19
#define NOBJ   256
#define BBATCH 8
#define HH     96
#define WW     96
#define NCHTOT 190                    // NBANCH*LCH
#define PLANE  (HH*WW)                // 9216
#define TOTCONF (BBATCH*NBANCH*PLANE) // 737280
#define NCONFBLK 720

__device__ __forceinline__ float ldat(const float* __restrict__ p, int b, int c, int hw) {
    return p[(size_t)(b * NCHTOT + c) * PLANE + hw];
}

// ws float layout (after 720 doubles of conf partials)
#define IOU_OFF 0
#define XY_OFF  2560
#define WH_OFF  5120
#define CO_OFF  7680
#define CLS_OFF 10240
#define SUB_OFF 12800

// ---------------- Kernel A: conf-sum partials (blocks 0..719) + per-grid/anchor
//                  gather+precompute (blocks 720..975) ----------------
__global__ __launch_bounds__(256) void fused_pre(const float* __restrict__ pred,
                                                 const float* __restrict__ targ,
                                                 const int* __restrict__ grids,
                                                 double* __restrict__ conf_part,
                                                 float* __restrict__ gw) {
    if (blockIdx.x < NCONFBLK) {
        int tid = blockIdx.x * 256 + threadIdx.x;          // 0 .. 184319
        int plane = tid / 2304;                            // 2304 float4 per plane
        int r = tid - plane * 2304;
        int b = plane / NBANCH;
        int g = plane - b * NBANCH;
        size_t off = (size_t)(b * NCHTOT + g * LCH) * PLANE + (size_t)r * 4;
        float4 t4 = *reinterpret_cast<const float4*>(targ + off);
        float4 p4 = *reinterpret_cast<const float4*>(pred + off);
        float dx = t4.x - p4.x, dy = t4.y - p4.y, dz = t4.z - p4.z, dw = t4.w - p4.w;
        double s = (double)(dx*dx) + (double)(dy*dy) + (double)(dz*dz) + (double)(dw*dw);
        for (int o = 32; o > 0; o >>= 1) s += __shfl_down(s, o, 64);
        __shared__ double wsum[4];
        int lane = threadIdx.x & 63, wid = threadIdx.x >> 6;
        if (lane == 0) wsum[wid] = s;
        __syncthreads();
        if (threadIdx.x == 0) conf_part[blockIdx.x] = wsum[0] + wsum[1] + wsum[2] + wsum[3];
        return;
    }

    // gather blocks: one grid each, threads 0..9 = anchors
    int gi = blockIdx.x - NCONFBLK;
    int a = threadIdx.x;
    if (a >= NBANCH) return;
    const int b = grids[gi*4+0], g = grids[gi*4+1], h = grids[gi*4+2], w = grids[gi*4+3];
    const int hw = h * WW + w;

    const float tc = ldat(targ, b, g*LCH+0, hw);
    const float tx = ldat(targ, b, g*LCH+1, hw);
    const float ty = ldat(targ, b, g*LCH+2, hw);
    const float tw = ldat(targ, b, g*LCH+3, hw);
    const float th = ldat(targ, b, g*LCH+4, hw);
    const float tb0 = tx - tw*0.5f, tb1 = ty - th*0.5f;
    const float tb2 = tx + tw*0.5f, tb3 = ty + th*0.5f;
    const float ta  = fabsf((tb2 - tb0) * (tb3 - tb1));

    const float pc = ldat(pred, b, a*LCH+0, hw);
    const float px = ldat(pred, b, a*LCH+1, hw);
    const float py = ldat(pred, b, a*LCH+2, hw);
    const float pw = ldat(pred, b, a*LCH+3, hw);
    const float ph = ldat(pred, b, a*LCH+4, hw);
    const float tca = ldat(targ, b, a*LCH+0, hw);   // targ conf at anchor a's channel

    const float pb0 = px - pw*0.5f, pb1 = py - ph*0.5f;
    const float pb2 = px + pw*0.5f, pb3 = py + ph*0.5f;
    float x1 = fmaxf(tb0, pb0), y1 = fmaxf(tb1, pb1);
    float x2 = fminf(tb2, pb2), y2 = fminf(tb3, pb3);
    float inter = fmaxf(x2 - x1, 0.f) * fmaxf(y2 - y1, 0.f);
    float pa = fabsf((pb2 - pb0) * (pb3 - pb1));
    float iou = inter / (((ta + pa) - inter) + 1e-6f);

    float dxl = tx - px, dyl = ty - py;
    float xy  = dxl*dxl + dyl*dyl;
    float dwl = sqrtf(fmaxf(tw, 0.f)) - sqrtf(fmaxf(pw, 0.f));
    float dhl = sqrtf(fmaxf(th, 0.f)) - sqrtf(fmaxf(ph, 0.f));
    float wh  = dwl*dwl + dhl*dhl;
    float dco = tc - pc;
    float co  = dco*dco;
    float dsb = tca - pc;
    float sub = dsb*dsb;

    float clsf = 0.f;
    #pragma unroll
    for (int c = 0; c < NCLS; ++c) {
        float d = ldat(pred, b, a*LCH+5+c, hw) - ldat(targ, b, b*LCH+5+c, hw);
        clsf += d * d;
    }
    float cls = clsf / 14.f;

    int idx = gi * NBANCH + a;
    gw[IOU_OFF + idx] = iou;
    gw[XY_OFF  + idx] = xy;
    gw[WH_OFF  + idx] = wh;
    gw[CO_OFF  + idx] = co;
    gw[CLS_OFF + idx] = cls;
    gw[SUB_OFF + idx] = sub;
}

// ---------------- Kernel B: parallel-Jacobi sel + combine (1 block, 256 threads) ----------------
__global__ __launch_bounds__(256) void yolo_main(const int* __restrict__ grids,
                                                 const double* __restrict__ conf_part,
                                                 const float* __restrict__ gw,
                                                 float* __restrict__ out) {
    __shared__ int packed[NOBJ];                    // (b<<24)|(g<<16)|(h<<8)|w
    __shared__ int sels[NOBJ];
    __shared__ int keys[NOBJ];
    __shared__ int changed;
    __shared__ double wpart[4][5];

    const int i = threadIdx.x;
    const int b = grids[i*4+0], g = grids[i*4+1], h = grids[i*4+2], w = grids[i*4+3];
    packed[i] = (b << 24) | (g << 16) | (h << 8) | w;

    // own IoU row in registers
    float iou_r[NBANCH];
    int afirst = 0;
    #pragma unroll
    for (int a = 0; a < NBANCH; ++a) {
        float v = gw[IOU_OFF + i*NBANCH + a];
        iou_r[a] = v;
        if (a >= 1 && afirst == 0 && v > 0.f) afirst = a;
    }
    sels[i] = afirst;          // exact for empty-mask grids (iou < 1 <= cur blocks updates)
    if (i == 0) changed = 0;
    __syncthreads();

    // ---- row-match mask (4 NAMED words -> registers, branchless, pipelined):
    //      j matches iff b_j==b_i && g_j==h_i && h_j==w_i ----
    const int mkey = (b << 16) | (h << 8) | w;
    unsigned long long m0 = 0, m1 = 0, m2 = 0, m3 = 0;
    #pragma unroll 8
    for (int j = 0; j < 64; ++j)
        m0 |= ((unsigned long long)((packed[j] >> 8) == mkey)) << j;
    #pragma unroll 8
    for (int j = 64; j < 128; ++j)
        m1 |= ((unsigned long long)((packed[j] >> 8) == mkey)) << (j - 64);
    #pragma unroll 8
    for (int j = 128; j < 192; ++j)
        m2 |= ((unsigned long long)((packed[j] >> 8) == mkey)) << (j - 128);
    #pragma unroll 8
    for (int j = 192; j < 256; ++j)
        m3 |= ((unsigned long long)((packed[j] >> 8) == mkey)) << (j - 192);

    const bool selfin = ((i < 64 ? m0 : i < 128 ? m1 : i < 192 ? m2 : m3) >> (i & 63)) & 1ull;
    // drop self bit from walk words
    unsigned long long w0 = m0, w1 = m1, w2 = m2, w3 = m3;
    if (i < 64)       w0 &= ~(1ull << i);
    else if (i < 128) w1 &= ~(1ull << (i - 64));
    else if (i < 192) w2 &= ~(1ull << (i - 128));
    else              w3 &= ~(1ull << (i - 192));

    const bool inS = (m0 | m1 | m2 | m3) != 0ull;
    const int kc = __popcll(m0) + __popcll(m1) + __popcll(m2) + __popcll(m3);

    // ---- parallel Jacobi to the unique DAG fixpoint.
    //      Step-k semantics: j<k final, j>k zero, j==k live cur (blocks only a==0). ----
    for (int round = 0; round < NOBJ; ++round) {
        int nv = sels[i];
        if (inS) {
            // build presence mask of row values (one mask walk per round)
            int present = selfin ? 1 : 0;
            unsigned long long mm;
            mm = w0; while (mm) { int j = __ffsll((long long)mm) - 1;       mm &= mm - 1; present |= 1 << ((j < i) ? sels[j] : 0); }
            mm = w1; while (mm) { int j = 64  + __ffsll((long long)mm) - 1; mm &= mm - 1; present |= 1 << ((j < i) ? sels[j] : 0); }
            mm = w2; while (mm) { int j = 128 + __ffsll((long long)mm) - 1; mm &= mm - 1; present |= 1 << ((j < i) ? sels[j] : 0); }
            mm = w3; while (mm) { int j = 192 + __ffsll((long long)mm) - 1; mm &= mm - 1; present |= 1 << ((j < i) ? sels[j] : 0); }
            int cur = 0;
            #pragma unroll
            for (int a = 0; a < NBANCH; ++a) {
                if ((float)cur < iou_r[a]) {
                    bool ok = ((a != 0) || (kc == 96)) && !((present >> a) & 1);
                    if (ok) cur = a;
                }
            }
            nv = cur;
        }
        __syncthreads();                                   // all reads of sels done
        if (inS && nv != sels[i]) { sels[i] = nv; changed = 1; }
        __syncthreads();                                   // writes + flag visible
        int c = changed;
        __syncthreads();                                   // all have read flag
        if (i == 0) changed = 0;                           // reset for next round
        if (!c) break;                                     // uniform exit
    }

    const int sel = sels[i];
    // ---- sel_xy = maxI[b, g, h, w=h]: nonzero only if that cell is a valid grid ----
    const int pkxy = (b << 24) | (g << 16) | (h << 8) | h;
    int sxy = 0;
    #pragma unroll 8
    for (int j = 0; j < NOBJ; ++j) {
        bool m = (packed[j] == pkxy);
        int v = sels[j];
        sxy = m ? v : sxy;
    }

    keys[i] = ((b * NBANCH + sel) * HH + h) * WW + w;
    __syncthreads();
    // ---- first-occurrence: branchless fixed-trip OR-scan (pipelined LDS reads) ----
    const int myk = keys[i];
    int dup = 0;
    #pragma unroll 8
    for (int j = 0; j < NOBJ; ++j) {
        dup |= (int)((j < i) & (keys[j] == myk));
    }
    const bool firstocc = (dup == 0);

    // ---- pick precomputed pieces ----
    double loc = (double)gw[XY_OFF + i*NBANCH + sxy] + (double)gw[WH_OFF + i*NBANCH + sel];
    double co  = (double)gw[CO_OFF + i*NBANCH + sel];
    double cls = (double)gw[CLS_OFF + i*NBANCH + sel];
    double sub = firstocc ? (double)gw[SUB_OFF + i*NBANCH + sel] : 0.0;

    // conf partial pickup: 720 doubles across 256 threads
    double cp = conf_part[i];
    if (i + 256 < NCONFBLK) cp += conf_part[i + 256];
    if (i + 512 < NCONFBLK) cp += conf_part[i + 512];

    // ---- wave-shuffle reduction, then 4 partials ----
    double v0 = loc, v1 = co, v2 = cls, v3 = sub, v4 = cp;
    #pragma unroll
    for (int o = 32; o > 0; o >>= 1) {
        v0 += __shfl_down(v0, o, 64);
        v1 += __shfl_down(v1, o, 64);
        v2 += __shfl_down(v2, o, 64);
        v3 += __shfl_down(v3, o, 64);
        v4 += __shfl_down(v4, o, 64);
    }
    const int lane = i & 63, wid = i >> 6;
    if (lane == 0) {
        wpart[wid][0] = v0; wpart[wid][1] = v1; wpart[wid][2] = v2;
        wpart[wid][3] = v3; wpart[wid][4] = v4;
    }
    __syncthreads();
    if (i == 0) {
        double s0 = 0, s1 = 0, s2 = 0, s3 = 0, s4 = 0;
        #pragma unroll
        for (int k = 0; k < 4; ++k) {
            s0 += wpart[k][0]; s1 += wpart[k][1]; s2 += wpart[k][2];
            s3 += wpart[k][3]; s4 += wpart[k][4];
        }
        double locS = s0 / 256.0;
        double coS  = s1 / 256.0;
        double clsS = s2 / 256.0;
        double cn   = (s4 - s3) / (double)TOTCONF;
        out[0] = (float)(7.0 * locS + 5.0 * coS + 5.0 * cn + clsS);
    }
}

extern "C" void kernel_launch(void* const* d_in, const int* in_sizes, int n_in,
                              void* d_out, int out_size, void* d_ws, size_t ws_size,
                              hipStream_t stream) {
    const float* pred = (const float*)d_in[0];
    const float* targ = (const float*)d_in[1];
    const int*  grids = (const int*)d_in[2];
    float* out = (float*)d_out;
    double* conf_part = (double*)d_ws;                       // 720 doubles
    float* gw = (float*)((char*)d_ws + NCONFBLK * sizeof(double));

    fused_pre<<<NCONFBLK + NOBJ, 256, 0, stream>>>(pred, targ, grids, conf_part, gw);
    yolo_main<<<1, 256, 0, stream>>>(grids, conf_part, gw, out);
}